// Round 1
// baseline (1132.878 us; speedup 1.0000x reference)
//
#include <hip/hip_runtime.h>

#define TT 8

__device__ __forceinline__ float lrelu(float x){ return fmaxf(x, 0.2f*x); }

// 2 cols x 2 samples register tile; srcT is transposed [i][sample] in LDS with row stride NSP
template<int NSP>
__device__ __forceinline__ void gemm22(const float* __restrict__ srcT, int so,
    const float* __restrict__ W, int ldw, int j0, int j1, int n, float acc[4]){
  float a00=0.f,a01=0.f,a10=0.f,a11=0.f;
  #pragma unroll 8
  for(int i=0;i<n;++i){
    float2 h = *(const float2*)(srcT + i*NSP + so);   // wave-uniform -> LDS broadcast
    float w0 = W[i*ldw + j0];
    float w1 = W[i*ldw + j1];
    a00 = fmaf(h.x,w0,a00); a01 = fmaf(h.y,w0,a01);
    a10 = fmaf(h.x,w1,a10); a11 = fmaf(h.y,w1,a11);
  }
  acc[0]=a00; acc[1]=a01; acc[2]=a10; acc[3]=a11;
}

// 1 col x 2 samples
template<int NSP>
__device__ __forceinline__ void gemm12(const float* __restrict__ srcT, int so,
    const float* __restrict__ W, int ldw, int j0, int n, float acc[2]){
  float a0=0.f,a1=0.f;
  #pragma unroll 8
  for(int i=0;i<n;++i){
    float2 h = *(const float2*)(srcT + i*NSP + so);
    float w = W[i*ldw + j0];
    a0 = fmaf(h.x,w,a0); a1 = fmaf(h.y,w,a1);
  }
  acc[0]=a0; acc[1]=a1;
}

// ---------------- Encoder kernel ----------------
// grid: 256 blocks = 64 sample-chunks (8 samples) x 4 t-groups {7,0},{6,1},{5,2},{4,3}
// each block: embed -> IVP (t-pair, lockstep, balanced 70 step-equivs) -> posterior -> mu/lv
extern "C" __global__ void __launch_bounds__(256)
k_enc(const float* __restrict__ features,
      const float* __restrict__ feW1, const float* __restrict__ feb1,
      const float* __restrict__ feW2, const float* __restrict__ feb2,
      const float* __restrict__ feW3, const float* __restrict__ feb3,
      const float* __restrict__ A1, const float* __restrict__ a1,
      const float* __restrict__ A2, const float* __restrict__ a2,
      const float* __restrict__ A3, const float* __restrict__ a3,
      const float* __restrict__ pW1, const float* __restrict__ pb1,
      const float* __restrict__ pW2, const float* __restrict__ pb2,
      float* __restrict__ ws_mu, float* __restrict__ ws_lv)
{
  __shared__ float ZT[2][64*10];    // transposed state per trajectory, pad 10
  __shared__ float H1T[128*10];
  __shared__ float H2T[128*10];
  const int tid=threadIdx.x, j=tid&63, sg=tid>>6, so=2*sg;
  const int g=blockIdx.x&3, chunk=blockIdx.x>>2, b0=chunk*8;
  int tval[2]; tval[0]=7-g; tval[1]=g;

  // loop-invariant per-thread weights (bias cols + A1 time row)
  const float a1j0=a1[j], a1j1=a1[j+64];
  const float wt0=A1[64*128+j], wt1=A1[64*128+j+64];
  const float a2j0=a2[j], a2j1=a2[j+64];
  const float a3j=a3[j];
  const float feb1j0=feb1[j], feb1j1=feb1[j+64], feb2j=feb2[j], feb3j=feb3[j];
  const float pb1j=pb1[j], pb2j0=pb2[j], pb2j1=pb2[j+64];

  // ---- embedding (both trajectories) ----
  for(int ti=0; ti<2; ++ti){
    const int tv=tval[ti];
    float acc[4]={0.f,0.f,0.f,0.f};
    const float* f0=features + ((size_t)(b0+so)*TT + tv)*6;
    const float* f1=features + ((size_t)(b0+so+1)*TT + tv)*6;
    #pragma unroll
    for(int i=0;i<6;++i){
      float w0=feW1[i*128+j], w1=feW1[i*128+j+64];
      float x0=f0[i], x1=f1[i];
      acc[0]=fmaf(x0,w0,acc[0]); acc[1]=fmaf(x1,w0,acc[1]);
      acc[2]=fmaf(x0,w1,acc[2]); acc[3]=fmaf(x1,w1,acc[3]);
    }
    __syncthreads();
    *(float2*)&H1T[j*10+so]      = make_float2(lrelu(acc[0]+feb1j0), lrelu(acc[1]+feb1j0));
    *(float2*)&H1T[(j+64)*10+so] = make_float2(lrelu(acc[2]+feb1j1), lrelu(acc[3]+feb1j1));
    __syncthreads();
    float a2v[2]; gemm12<10>(H1T, so, feW2, 64, j, 128, a2v);
    *(float2*)&H2T[j*10+so] = make_float2(lrelu(a2v[0]+feb2j), lrelu(a2v[1]+feb2j));
    __syncthreads();
    float a3v[2]; gemm12<10>(H2T, so, feW3, 64, j, 64, a3v);
    *(float2*)&ZT[ti][j*10+so] = make_float2(a3v[0]+feb3j, a3v[1]+feb3j);
    __syncthreads();
  }

  // ---- Euler IVP, adt = -0.1, t_k = 0.1*k ----
  const int sa=10*tval[0], sb=10*tval[1];
  auto step=[&](float* Z, float tk){
    float acc[4];
    gemm22<10>(Z, so, A1, 128, j, j+64, 64, acc);
    float2 h0 = make_float2(tanhf(fmaf(tk,wt0,acc[0])+a1j0), tanhf(fmaf(tk,wt0,acc[1])+a1j0));
    float2 h1 = make_float2(tanhf(fmaf(tk,wt1,acc[2])+a1j1), tanhf(fmaf(tk,wt1,acc[3])+a1j1));
    *(float2*)&H1T[j*10+so]=h0;
    *(float2*)&H1T[(j+64)*10+so]=h1;
    __syncthreads();
    gemm22<10>(H1T, so, A2, 128, j, j+64, 128, acc);
    float2 g0=make_float2(tanhf(acc[0]+a2j0), tanhf(acc[1]+a2j0));
    float2 g1=make_float2(tanhf(acc[2]+a2j1), tanhf(acc[3]+a2j1));
    *(float2*)&H2T[j*10+so]=g0;
    *(float2*)&H2T[(j+64)*10+so]=g1;
    __syncthreads();
    float d[2]; gemm12<10>(H2T, so, A3, 64, j, 128, d);
    float2 z=*(float2*)&Z[j*10+so];
    z.x = fmaf(-0.1f, d[0]+a3j, z.x);
    z.y = fmaf(-0.1f, d[1]+a3j, z.y);
    *(float2*)&Z[j*10+so]=z;
    __syncthreads();
  };
  for(int k=0;k<sa;++k){
    float tk=0.1f*(float)k;
    step(ZT[0], tk);
    if(k<sb) step(ZT[1], tk);      // uniform branch: barriers are safe
  }

  // ---- posterior for both t values ----
  for(int ti=0; ti<2; ++ti){
    const int tv=tval[ti];
    float ph[2]; gemm12<10>(ZT[ti], so, pW1, 64, j, 64, ph);
    __syncthreads();
    *(float2*)&H1T[j*10+so]=make_float2(lrelu(ph[0]+pb1j), lrelu(ph[1]+pb1j));
    __syncthreads();
    float p[4]; gemm22<10>(H1T, so, pW2, 128, j, j+64, 64, p);
    size_t o0=((size_t)(b0+so)*TT+tv)*64+j;
    size_t o1=((size_t)(b0+so+1)*TT+tv)*64+j;
    ws_mu[o0]=p[0]+pb2j0; ws_mu[o1]=p[1]+pb2j0;
    ws_lv[o0]=p[2]+pb2j1; ws_lv[o1]=p[3]+pb2j1;
    __syncthreads();
  }
}

// ---------------- Decoder kernel ----------------
// grid: 128 blocks x 4 samples; mixing+softmax+reparam, ONE shared 70-step trajectory
// (all _ivp(z0,t) are prefixes: adt=+0.1, same time grid), record every 10 steps, rec MLP.
extern "C" __global__ void __launch_bounds__(256)
k_dec(const float* __restrict__ mu_g, const float* __restrict__ lv_g,
      const float* __restrict__ eps,
      const float* __restrict__ mxW1, const float* __restrict__ mxb1,
      const float* __restrict__ mxW2, const float* __restrict__ mxb2,
      const float* __restrict__ A1, const float* __restrict__ a1,
      const float* __restrict__ A2, const float* __restrict__ a2,
      const float* __restrict__ A3, const float* __restrict__ a3,
      const float* __restrict__ rW1, const float* __restrict__ rb1,
      const float* __restrict__ rW2, const float* __restrict__ rb2,
      const float* __restrict__ rW3, const float* __restrict__ rb3,
      float* __restrict__ out)
{
  __shared__ float mu_s[2048];      // [s][t][j]
  __shared__ float lv_s[2048];
  __shared__ float mh_s[1024];      // [s][t][c]
  __shared__ float wl_s[32];        // [s][t]
  __shared__ float ZT[64*5];        // transposed state, pad 5
  __shared__ float H1T[128*5];
  __shared__ float H2T[128*5];
  __shared__ float LATT[TT][256];   // [t][i*4+s]
  const int tid=threadIdx.x, j=tid&63, sg=tid>>6;
  const int b0=blockIdx.x*4;

  for(int idx=tid; idx<2048; idx+=256){
    mu_s[idx]=mu_g[(size_t)b0*512+idx];
    lv_s[idx]=lv_g[(size_t)b0*512+idx];
  }
  __syncthreads();
  // mixing hidden: mh[s][t][c] = lrelu(mu . mxW1 + b)
  for(int idx=tid; idx<1024; idx+=256){
    int s=idx>>8, t=(idx>>5)&7, c=idx&31;
    float a=0.f;
    #pragma unroll 8
    for(int i=0;i<64;++i) a=fmaf(mu_s[(s*8+t)*64+i], mxW1[i*32+c], a);
    mh_s[idx]=lrelu(a+mxb1[c]);
  }
  __syncthreads();
  if(tid<32){
    int s=tid>>3, t=tid&7;
    float a=0.f;
    #pragma unroll
    for(int i=0;i<32;++i) a=fmaf(mh_s[(s*8+t)*32+i], mxW2[i], a);
    wl_s[tid]=a+mxb2[0];
  }
  __syncthreads();
  // softmax over t, weighted mu0/lv0, reparameterize -> z0
  {
    int s=sg;
    float m=-1e30f;
    #pragma unroll
    for(int t=0;t<8;++t) m=fmaxf(m, wl_s[s*8+t]);
    float e[8], Zs=0.f;
    #pragma unroll
    for(int t=0;t<8;++t){ e[t]=expf(wl_s[s*8+t]-m); Zs+=e[t]; }
    float inv=1.f/Zs;
    float mu0=0.f, lv0=0.f;
    #pragma unroll
    for(int t=0;t<8;++t){
      float w=e[t]*inv;
      mu0=fmaf(w, mu_s[(s*8+t)*64+j], mu0);
      lv0=fmaf(w, lv_s[(s*8+t)*64+j], lv0);
    }
    float z0 = fmaf(eps[(size_t)(b0+s)*64+j], expf(0.5f*lv0), mu0);
    ZT[j*5+s]=z0;
    LATT[0][j*4+s]=z0;
  }
  __syncthreads();

  const float a1j0=a1[j], a1j1=a1[j+64];
  const float wt0=A1[64*128+j], wt1=A1[64*128+j+64];
  const float a2j0=a2[j], a2j1=a2[j+64], a3j=a3[j];

  for(int k=0;k<70;++k){
    float tk=0.1f*(float)k;
    float acc0=0.f, acc1=0.f;
    #pragma unroll 8
    for(int i=0;i<64;++i){
      float h=ZT[i*5+sg];
      acc0=fmaf(h, A1[i*128+j], acc0);
      acc1=fmaf(h, A1[i*128+j+64], acc1);
    }
    H1T[j*5+sg]      = tanhf(fmaf(tk,wt0,acc0)+a1j0);
    H1T[(j+64)*5+sg] = tanhf(fmaf(tk,wt1,acc1)+a1j1);
    __syncthreads();
    acc0=0.f; acc1=0.f;
    #pragma unroll 8
    for(int i=0;i<128;++i){
      float h=H1T[i*5+sg];
      acc0=fmaf(h, A2[i*128+j], acc0);
      acc1=fmaf(h, A2[i*128+j+64], acc1);
    }
    H2T[j*5+sg]      = tanhf(acc0+a2j0);
    H2T[(j+64)*5+sg] = tanhf(acc1+a2j1);
    __syncthreads();
    float d=0.f;
    #pragma unroll 8
    for(int i=0;i<128;++i) d=fmaf(H2T[i*5+sg], A3[i*64+j], d);
    ZT[j*5+sg] = fmaf(0.1f, d+a3j, ZT[j*5+sg]);
    if(((k+1)%10)==0) LATT[(k+1)/10][j*4+sg]=ZT[j*5+sg];
    __syncthreads();
  }

  // reconstruction MLP per t
  for(int t=0;t<TT;++t){
    float acc0=0.f, acc1=0.f;
    #pragma unroll 8
    for(int i=0;i<64;++i){
      float h=LATT[t][i*4+sg];
      acc0=fmaf(h, rW1[i*128+j], acc0);
      acc1=fmaf(h, rW1[i*128+j+64], acc1);
    }
    __syncthreads();
    H1T[j*5+sg]=lrelu(acc0+rb1[j]);
    H1T[(j+64)*5+sg]=lrelu(acc1+rb1[j+64]);
    __syncthreads();
    float a=0.f;
    #pragma unroll 8
    for(int i=0;i<128;++i) a=fmaf(H1T[i*5+sg], rW2[i*64+j], a);
    H2T[j*5+sg]=lrelu(a+rb2[j]);
    __syncthreads();
    if(tid<8){
      int s=tid>>1, o=tid&1;
      float av=0.f;
      #pragma unroll 8
      for(int i=0;i<64;++i) av=fmaf(H2T[i*5+s], rW3[i*2+o], av);
      out[((size_t)(b0+s)*TT+t)*2+o]=av+rb3[o];
    }
    __syncthreads();
  }
}

extern "C" void kernel_launch(void* const* d_in, const int* in_sizes, int n_in,
                              void* d_out, int out_size, void* d_ws, size_t ws_size,
                              hipStream_t stream){
  const float* features=(const float*)d_in[0];
  const float* eps     =(const float*)d_in[1];
  const float* feW1=(const float*)d_in[2];  const float* feb1=(const float*)d_in[3];
  const float* feW2=(const float*)d_in[4];  const float* feb2=(const float*)d_in[5];
  const float* feW3=(const float*)d_in[6];  const float* feb3=(const float*)d_in[7];
  const float* eA1=(const float*)d_in[8];   const float* ea1=(const float*)d_in[9];
  const float* eA2=(const float*)d_in[10];  const float* ea2=(const float*)d_in[11];
  const float* eA3=(const float*)d_in[12];  const float* ea3=(const float*)d_in[13];
  const float* pW1=(const float*)d_in[14];  const float* pb1=(const float*)d_in[15];
  const float* pW2=(const float*)d_in[16];  const float* pb2=(const float*)d_in[17];
  const float* mxW1=(const float*)d_in[18]; const float* mxb1=(const float*)d_in[19];
  const float* mxW2=(const float*)d_in[20]; const float* mxb2=(const float*)d_in[21];
  const float* dA1=(const float*)d_in[22];  const float* da1=(const float*)d_in[23];
  const float* dA2=(const float*)d_in[24];  const float* da2=(const float*)d_in[25];
  const float* dA3=(const float*)d_in[26];  const float* da3=(const float*)d_in[27];
  const float* rW1=(const float*)d_in[28];  const float* rb1=(const float*)d_in[29];
  const float* rW2=(const float*)d_in[30];  const float* rb2=(const float*)d_in[31];
  const float* rW3=(const float*)d_in[32];  const float* rb3=(const float*)d_in[33];

  float* ws_mu=(float*)d_ws;
  float* ws_lv=ws_mu + 512*8*64;   // 1 MB each, well within ws

  k_enc<<<dim3(256),dim3(256),0,stream>>>(features,
      feW1,feb1,feW2,feb2,feW3,feb3,
      eA1,ea1,eA2,ea2,eA3,ea3,
      pW1,pb1,pW2,pb2,
      ws_mu, ws_lv);
  k_dec<<<dim3(128),dim3(256),0,stream>>>(ws_mu, ws_lv, eps,
      mxW1,mxb1,mxW2,mxb2,
      dA1,da1,dA2,da2,dA3,da3,
      rW1,rb1,rW2,rb2,rW3,rb3,
      (float*)d_out);
}